// Round 16
// baseline (435.532 us; speedup 1.0000x reference)
//
#include <hip/hip_runtime.h>

#define H 128
#define H2 256
#define NODE_IN 32
#define BN_EPS 1e-5f

typedef __bf16 bf16x8 __attribute__((ext_vector_type(8)));
typedef __bf16 bf16x4 __attribute__((ext_vector_type(4)));
typedef float f32x4 __attribute__((ext_vector_type(4)));

#define MFMA(a, b, c) __builtin_amdgcn_mfma_f32_16x16x32_bf16(a, b, c, 0, 0, 0)

// ---------------------------------------------------------------------------
// Weights -> bf16, transposed, XOR-swizzled GLOBAL layout.
// W1 [L][128][256] -> per layer at l*131072       : row n(0..255) x 256B
// W2 [L][256][128] -> per layer at l*131072+65536 : row n(0..127) x 512B
// embW [32][128]   -> at L*131072: Wt_e[c][k], row c(0..127) x 64B (no swizzle)
// Swizzle: 16B chunk c' = c ^ (n & 7) within each row.
__global__ __launch_bounds__(256) void convert_weights_kernel(
    const float* __restrict__ W1, const float* __restrict__ W2,
    const float* __restrict__ embW, char* __restrict__ Ws, int L)
{
    int idx = blockIdx.x * 256 + threadIdx.x;
    int per = H * H2;
    int total = L * per;
    if (idx < total) {
        int l = idx / per, r = idx % per;
        int k = r / H2, n = r % H2;          // W1[l][k][n]
        int c = k >> 3, e = k & 7;
        size_t off = (size_t)l * 131072 + n * 256 + (((c ^ (n & 7)) << 4)) + e * 2;
        *(__bf16*)(Ws + off) = (__bf16)W1[idx];
    } else if (idx < 2 * total) {
        int j = idx - total;
        int l = j / per, r = j % per;
        int k = r / H, n = r % H;            // W2[l][k][n]
        int c = k >> 3, e = k & 7;
        size_t off = (size_t)l * 131072 + 65536 + n * 512 + (((c ^ (n & 7)) << 4)) + e * 2;
        *(__bf16*)(Ws + off) = (__bf16)W2[j];
    } else if (idx < 2 * total + H * NODE_IN) {
        int j = idx - 2 * total;
        int k = j / H, c = j % H;            // embW[k][c]
        size_t off = (size_t)L * 131072 + c * 64 + k * 2;
        *(__bf16*)(Ws + off) = (__bf16)embW[j];
    }
}

// ---------------------------------------------------------------------------
// h0 = x @ emb_W + emb_b via MFMA (K=32 = one mfma_16x16x32).
__global__ __launch_bounds__(512) void embed_kernel(
    const float* __restrict__ x, const char* __restrict__ Wse,
    const float* __restrict__ bias, __bf16* __restrict__ h, int N)
{
    int tid = threadIdx.x;
    int w = tid >> 6, lane = tid & 63;
    int l15 = lane & 15, kg = lane >> 4;

    bf16x8 aw[8];
#pragma unroll
    for (int nt = 0; nt < 8; ++nt)
        aw[nt] = *(const bf16x8*)(Wse + (nt * 16 + l15) * 64 + kg * 16);

    int r = (blockIdx.x * 8 + w) * 16 + l15;
    bool ok = (r < N);

    bf16x8 xb = {};
    if (ok) {
        float4 v0 = *(const float4*)&x[(size_t)r * NODE_IN + kg * 8];
        float4 v1 = *(const float4*)&x[(size_t)r * NODE_IN + kg * 8 + 4];
        xb[0] = (__bf16)v0.x; xb[1] = (__bf16)v0.y;
        xb[2] = (__bf16)v0.z; xb[3] = (__bf16)v0.w;
        xb[4] = (__bf16)v1.x; xb[5] = (__bf16)v1.y;
        xb[6] = (__bf16)v1.z; xb[7] = (__bf16)v1.w;
    }

    __bf16* hr = h + (size_t)r * H;
#pragma unroll
    for (int nt = 0; nt < 8; ++nt) {
        f32x4 acc = {0.f, 0.f, 0.f, 0.f};
        acc = MFMA(aw[nt], xb, acc);
        if (ok) {
            float4 bb = *(const float4*)&bias[nt * 16 + kg * 4];
            bf16x4 hv;
            hv[0] = (__bf16)(acc[0] + bb.x);
            hv[1] = (__bf16)(acc[1] + bb.y);
            hv[2] = (__bf16)(acc[2] + bb.z);
            hv[3] = (__bf16)(acc[3] + bb.w);
            *(bf16x4*)(hr + nt * 16 + kg * 4) = hv;
        }
    }
}

// ---------------------------------------------------------------------------
// CSR build
__global__ __launch_bounds__(256) void hist_kernel(
    const int* __restrict__ dst, int* __restrict__ deg, int E)
{
    int e = blockIdx.x * 256 + threadIdx.x;
    if (e < E) atomicAdd(&deg[dst[e]], 1);
}

__global__ __launch_bounds__(256) void scan_partial_kernel(
    const int* __restrict__ deg, int* __restrict__ bsum, int N)
{
    __shared__ int red[256];
    int b = blockIdx.x, t = threadIdx.x;
    int base = b * 2048 + t * 8;
    int s = 0;
#pragma unroll
    for (int i = 0; i < 8; ++i) { int idx = base + i; if (idx < N) s += deg[idx]; }
    red[t] = s;
    __syncthreads();
    for (int d = 128; d > 0; d >>= 1) {
        if (t < d) red[t] += red[t + d];
        __syncthreads();
    }
    if (t == 0) bsum[b] = red[0];
}

__global__ __launch_bounds__(256) void scan_bsum_kernel(
    int* __restrict__ bsum, int* __restrict__ total, int numB)
{
    __shared__ int ts[256];
    int t = threadIdx.x;
    int v = (t < numB) ? bsum[t] : 0;
    ts[t] = v;
    __syncthreads();
    for (int d = 1; d < 256; d <<= 1) {
        int u = (t >= d) ? ts[t - d] : 0;
        __syncthreads();
        ts[t] += u;
        __syncthreads();
    }
    if (t < numB) bsum[t] = ts[t] - v;
    if (t == 255) *total = ts[255];
}

__global__ __launch_bounds__(256) void scan_apply_kernel(
    const int* __restrict__ deg, const int* __restrict__ bsum,
    int* __restrict__ offp, int* __restrict__ cursor, int N)
{
    __shared__ int ts[256];
    int b = blockIdx.x, t = threadIdx.x;
    int base = b * 2048 + t * 8;
    int loc[8];
    int s = 0;
#pragma unroll
    for (int i = 0; i < 8; ++i) {
        int idx = base + i;
        loc[i] = (idx < N) ? deg[idx] : 0;
        s += loc[i];
    }
    ts[t] = s;
    __syncthreads();
    for (int d = 1; d < 256; d <<= 1) {
        int u = (t >= d) ? ts[t - d] : 0;
        __syncthreads();
        ts[t] += u;
        __syncthreads();
    }
    int run = bsum[b] + ts[t] - s;
#pragma unroll
    for (int i = 0; i < 8; ++i) {
        int idx = base + i;
        if (idx < N) { offp[idx] = run; cursor[idx] = run; }
        run += loc[i];
    }
}

__global__ __launch_bounds__(256) void fill_kernel(
    const int* __restrict__ src, const int* __restrict__ dst,
    int* __restrict__ cursor, int* __restrict__ srclist, int E)
{
    int e = blockIdx.x * 256 + threadIdx.x;
    if (e < E) {
        int pos = atomicAdd(&cursor[dst[e]], 1);
        srclist[pos] = src[e];
    }
}

// ---------------------------------------------------------------------------
__device__ __forceinline__ uint32_t pack_relu2(float x, float y) {
    __bf16 a = (__bf16)fmaxf(x, 0.f), b = (__bf16)fmaxf(y, 0.f);
    return (uint32_t)__builtin_bit_cast(uint16_t, a) |
           ((uint32_t)__builtin_bit_cast(uint16_t, b) << 16);
}

// ---------------------------------------------------------------------------
// Fused GIN layer: pure-sum gather (h is already post-BN+ReLU) -> LDS tile ->
// relu(z@W1+b1)@W2+b2 -> zpb (pre-BN) + BN partial stats.
// Block = 8 waves x 32 rows. Gather: each wave gathers 4 rows in ONE pass
// (16 lanes/node x 8 cols) into 8KB XOR-swizzled LDS zt. Phase1 reads zt
// from LDS (A=W1 reg frags), hid via 16KB swizzled LDS; phase2 as before.
// LDS ~25.6KB -> 4 blocks/CU (wave-slot limited, 32 waves/CU).
__global__ __launch_bounds__(512, 4) void gin_layer_kernel(
    const __bf16* __restrict__ hin, __bf16* __restrict__ zpb,
    const int* __restrict__ offp, const int* __restrict__ srclist,
    const char* __restrict__ Ws, const float* __restrict__ b1l,
    const float* __restrict__ b2l, float* __restrict__ spart, int N)
{
    __shared__ __align__(16) char zt[8192];    // 32 rows x 256B, swizzled
    __shared__ __align__(16) char hl[16384];   // 32 rows x 512B, swizzled
    __shared__ float sstat[256];

    int tid = threadIdx.x;
    int w = tid >> 6, lane = tid & 63;
    int l15 = lane & 15, kg = lane >> 4;
    const int xsw = (l15 & 7) << 4;
    int r0g = blockIdx.x * 32;

    if (tid < 256) sstat[tid] = 0.f;

    // ---- phase-1 weight frags issued early (hide L2 latency under gather) --
    bf16x8 aW1[2][4];
#pragma unroll
    for (int nt = 0; nt < 2; ++nt)
#pragma unroll
        for (int kk = 0; kk < 4; ++kk)
            aW1[nt][kk] = *(const bf16x8*)(
                Ws + (w * 32 + nt * 16 + l15) * 256 + ((((kk * 4 + kg) << 4)) ^ xsw));
    float4 bb1[2];
#pragma unroll
    for (int nt = 0; nt < 2; ++nt)
        bb1[nt] = *(const float4*)&b1l[w * 32 + nt * 16 + kg * 4];

    // ---- gather: wave w fills local rows [w*4, w*4+4) of zt (pure sum) ----
    {
        int rl = w * 4 + kg;
        int r = r0g + rl;
        bf16x8 o = {};
        if (r < N) {
            float acc[8];
            bf16x8 sv = *(const bf16x8*)(hin + (size_t)r * H + l15 * 8);
#pragma unroll
            for (int j = 0; j < 8; ++j) acc[j] = (float)sv[j];
            int i0 = offp[r], i1 = offp[r + 1];
            int i = i0;
            for (; i + 3 < i1; i += 4) {
                int s0 = srclist[i], s1 = srclist[i + 1];
                int s2 = srclist[i + 2], s3 = srclist[i + 3];
                bf16x8 u0 = *(const bf16x8*)(hin + (size_t)s0 * H + l15 * 8);
                bf16x8 u1 = *(const bf16x8*)(hin + (size_t)s1 * H + l15 * 8);
                bf16x8 u2 = *(const bf16x8*)(hin + (size_t)s2 * H + l15 * 8);
                bf16x8 u3 = *(const bf16x8*)(hin + (size_t)s3 * H + l15 * 8);
#pragma unroll
                for (int j = 0; j < 8; ++j)
                    acc[j] += ((float)u0[j] + (float)u1[j]) +
                              ((float)u2[j] + (float)u3[j]);
            }
            for (; i < i1; ++i) {
                int s0 = srclist[i];
                bf16x8 u0 = *(const bf16x8*)(hin + (size_t)s0 * H + l15 * 8);
#pragma unroll
                for (int j = 0; j < 8; ++j) acc[j] += (float)u0[j];
            }
#pragma unroll
            for (int j = 0; j < 8; ++j) o[j] = (__bf16)acc[j];
        }
        int chunk = l15 ^ (rl & 7);
        *(bf16x8*)(zt + rl * 256 + chunk * 16) = o;
    }
    __syncthreads();   // zt complete

    // ---- phase 1: GEMM1 from LDS zt into LDS hid ----
#pragma unroll 1
    for (int i = 0; i < 2; ++i) {
        int rl = i * 16 + l15;
        bf16x8 zb[4];
#pragma unroll
        for (int kk = 0; kk < 4; ++kk)
            zb[kk] = *(const bf16x8*)(zt + rl * 256 + ((((kk * 4 + kg) << 4)) ^ xsw));
#pragma unroll
        for (int nt = 0; nt < 2; ++nt) {
            f32x4 a = {0.f, 0.f, 0.f, 0.f};
            a = MFMA(aW1[nt][0], zb[0], a);
            a = MFMA(aW1[nt][1], zb[1], a);
            a = MFMA(aW1[nt][2], zb[2], a);
            a = MFMA(aW1[nt][3], zb[3], a);
            uint32_t p0 = pack_relu2(a[0] + bb1[nt].x, a[1] + bb1[nt].y);
            uint32_t p1 = pack_relu2(a[2] + bb1[nt].z, a[3] + bb1[nt].w);
            int chunk = (w * 4 + nt * 2 + (kg >> 1)) ^ (l15 & 7);
            uint32_t* dstp = (uint32_t*)(hl + rl * 512 + chunk * 16 + (kg & 1) * 8);
            dstp[0] = p0;
            dstp[1] = p1;
        }
    }

    // ---- phase 2 weights/bias (aW1 dead; aW2 replaces it) ----
    bf16x8 aW2[8];
#pragma unroll
    for (int kk = 0; kk < 8; ++kk)
        aW2[kk] = *(const bf16x8*)(
            Ws + 65536 + (w * 16 + l15) * 512 + ((((kk * 4 + kg) << 4)) ^ xsw));
    float4 bb2 = *(const float4*)&b2l[w * 16 + kg * 4];

    __syncthreads();   // hid complete

    // ---- phase 2: GEMM2 from LDS hid; wave w owns out cols [w*16,w*16+16) --
    float ps0 = 0.f, ps1 = 0.f, ps2 = 0.f, ps3 = 0.f;
    float pq0 = 0.f, pq1 = 0.f, pq2 = 0.f, pq3 = 0.f;
#pragma unroll 1
    for (int i = 0; i < 2; ++i) {
        int r = r0g + i * 16 + l15;
        bool ok = (r < N);
        int rl = i * 16 + l15;
        bf16x8 bd[8];
#pragma unroll
        for (int kk = 0; kk < 8; ++kk)
            bd[kk] = *(const bf16x8*)(hl + rl * 512 + ((((kk * 4 + kg) << 4)) ^ xsw));
        f32x4 c = {0.f, 0.f, 0.f, 0.f};
#pragma unroll
        for (int kk = 0; kk < 8; ++kk) c = MFMA(aW2[kk], bd[kk], c);
        if (ok) {
            float v0 = c[0] + bb2.x, v1 = c[1] + bb2.y;
            float v2 = c[2] + bb2.z, v3 = c[3] + bb2.w;
            bf16x4 ov;
            ov[0] = (__bf16)v0; ov[1] = (__bf16)v1;
            ov[2] = (__bf16)v2; ov[3] = (__bf16)v3;
            *(bf16x4*)(zpb + (size_t)r * H + w * 16 + kg * 4) = ov;
            ps0 += v0; pq0 += v0 * v0;
            ps1 += v1; pq1 += v1 * v1;
            ps2 += v2; pq2 += v2 * v2;
            ps3 += v3; pq3 += v3 * v3;
        }
    }

    // reduce over the 16 l15-lanes; wave-disjoint cols -> plain LDS stores
    ps0 += __shfl_xor(ps0, 1, 64); ps0 += __shfl_xor(ps0, 2, 64);
    ps0 += __shfl_xor(ps0, 4, 64); ps0 += __shfl_xor(ps0, 8, 64);
    ps1 += __shfl_xor(ps1, 1, 64); ps1 += __shfl_xor(ps1, 2, 64);
    ps1 += __shfl_xor(ps1, 4, 64); ps1 += __shfl_xor(ps1, 8, 64);
    ps2 += __shfl_xor(ps2, 1, 64); ps2 += __shfl_xor(ps2, 2, 64);
    ps2 += __shfl_xor(ps2, 4, 64); ps2 += __shfl_xor(ps2, 8, 64);
    ps3 += __shfl_xor(ps3, 1, 64); ps3 += __shfl_xor(ps3, 2, 64);
    ps3 += __shfl_xor(ps3, 4, 64); ps3 += __shfl_xor(ps3, 8, 64);
    pq0 += __shfl_xor(pq0, 1, 64); pq0 += __shfl_xor(pq0, 2, 64);
    pq0 += __shfl_xor(pq0, 4, 64); pq0 += __shfl_xor(pq0, 8, 64);
    pq1 += __shfl_xor(pq1, 1, 64); pq1 += __shfl_xor(pq1, 2, 64);
    pq1 += __shfl_xor(pq1, 4, 64); pq1 += __shfl_xor(pq1, 8, 64);
    pq2 += __shfl_xor(pq2, 1, 64); pq2 += __shfl_xor(pq2, 2, 64);
    pq2 += __shfl_xor(pq2, 4, 64); pq2 += __shfl_xor(pq2, 8, 64);
    pq3 += __shfl_xor(pq3, 1, 64); pq3 += __shfl_xor(pq3, 2, 64);
    pq3 += __shfl_xor(pq3, 4, 64); pq3 += __shfl_xor(pq3, 8, 64);
    if (l15 == 0) {
        int cb = w * 16 + kg * 4;
        sstat[cb + 0] = ps0; sstat[cb + 1] = ps1;
        sstat[cb + 2] = ps2; sstat[cb + 3] = ps3;
        sstat[H + cb + 0] = pq0; sstat[H + cb + 1] = pq1;
        sstat[H + cb + 2] = pq2; sstat[H + cb + 3] = pq3;
    }
    __syncthreads();
    if (tid < 256) spart[(size_t)blockIdx.x * 256 + tid] = sstat[tid];
}

// ---------------------------------------------------------------------------
__global__ __launch_bounds__(256) void reduce_stats_kernel(
    const float* __restrict__ spart, float* __restrict__ stats, int R)
{
    int t = threadIdx.x;
    int b = blockIdx.x;
    int per = (R + gridDim.x - 1) / gridDim.x;
    int r0 = b * per, r1 = r0 + per;
    if (r1 > R) r1 = R;
    float s = 0.f;
    for (int r = r0; r < r1; ++r) s += spart[(size_t)r * 256 + t];
    atomicAdd(&stats[t], s);
}

// ---------------------------------------------------------------------------
__global__ void bn_finalize_kernel(const float* __restrict__ stats,
                                   const float* __restrict__ gamma,
                                   const float* __restrict__ beta,
                                   float* __restrict__ ss, int N)
{
    int j = threadIdx.x;
    float invN = 1.0f / (float)N;
    float mean = stats[j] * invN;
    float var = stats[H + j] * invN - mean * mean;
    float sc = gamma[j] * rsqrtf(var + BN_EPS);
    ss[j] = sc;
    ss[H + j] = beta[j] - mean * sc;
}

// ---------------------------------------------------------------------------
// h = bf16(relu(zpb*scale + shift))  (materialize post-BN h for next gather)
__global__ __launch_bounds__(256) void bn_apply_bf16_kernel(
    const __bf16* __restrict__ zpb, const float* __restrict__ ss,
    __bf16* __restrict__ h, int N)
{
    size_t i = (size_t)blockIdx.x * 256 + threadIdx.x;   // 8-elem units
    size_t total = (size_t)N * (H / 8);
    if (i >= total) return;
    int c8 = (int)(i & (H / 8 - 1));
    bf16x8 v = *(const bf16x8*)(zpb + i * 8);
    const float* scp = &ss[c8 * 8];
    const float* shp = &ss[H + c8 * 8];
    bf16x8 o;
#pragma unroll
    for (int j = 0; j < 8; ++j)
        o[j] = (__bf16)fmaxf((float)v[j] * scp[j] + shp[j], 0.f);
    *(bf16x8*)(h + i * 8) = o;
}

// ---------------------------------------------------------------------------
// out = relu(zpb*scale + shift), bf16 -> fp32 (final layer)
__global__ __launch_bounds__(256) void bn_apply_kernel(
    const __bf16* __restrict__ zpb, const float* __restrict__ ss,
    float* __restrict__ out, int N)
{
    size_t i = (size_t)blockIdx.x * 256 + threadIdx.x;   // 8-elem units
    size_t total = (size_t)N * (H / 8);
    if (i >= total) return;
    int c8 = (int)(i & (H / 8 - 1));
    bf16x8 v = *(const bf16x8*)(zpb + i * 8);
    float4 o0, o1;
    const float* scp = &ss[c8 * 8];
    const float* shp = &ss[H + c8 * 8];
    o0.x = fmaxf((float)v[0] * scp[0] + shp[0], 0.f);
    o0.y = fmaxf((float)v[1] * scp[1] + shp[1], 0.f);
    o0.z = fmaxf((float)v[2] * scp[2] + shp[2], 0.f);
    o0.w = fmaxf((float)v[3] * scp[3] + shp[3], 0.f);
    o1.x = fmaxf((float)v[4] * scp[4] + shp[4], 0.f);
    o1.y = fmaxf((float)v[5] * scp[5] + shp[5], 0.f);
    o1.z = fmaxf((float)v[6] * scp[6] + shp[6], 0.f);
    o1.w = fmaxf((float)v[7] * scp[7] + shp[7], 0.f);
    ((float4*)out)[i * 2] = o0;
    ((float4*)out)[i * 2 + 1] = o1;
}

// ---------------------------------------------------------------------------
static inline char* align_up(char* p, size_t a) {
    return (char*)(((uintptr_t)p + a - 1) & ~(uintptr_t)(a - 1));
}

extern "C" void kernel_launch(void* const* d_in, const int* in_sizes, int n_in,
                              void* d_out, int out_size, void* d_ws, size_t ws_size,
                              hipStream_t stream)
{
    const float* x    = (const float*)d_in[0];
    const int*   ei   = (const int*)d_in[1];
    const float* embW = (const float*)d_in[2];
    const float* embb = (const float*)d_in[3];
    const float* W1   = (const float*)d_in[4];
    const float* b1   = (const float*)d_in[5];
    const float* W2   = (const float*)d_in[6];
    const float* b2   = (const float*)d_in[7];
    const float* gamma= (const float*)d_in[8];
    const float* beta = (const float*)d_in[9];

    int N = in_sizes[0] / NODE_IN;
    int E = in_sizes[1] / 2;
    int L = in_sizes[4] / (H * H2);
    const int* src = ei;
    const int* dst = ei + E;

    int numB = (N + 2047) / 2048;
    int nblk = (N + 31) / 32;        // 32 rows per block

    char* w = (char*)d_ws;
    __bf16* hbuf = (__bf16*)w;   w += (size_t)N * H * sizeof(__bf16);
    w = align_up(w, 256);
    __bf16* zpb = (__bf16*)w;    w += (size_t)N * H * sizeof(__bf16);
    w = align_up(w, 256);
    float* spart = (float*)w;    w += (size_t)nblk * 256 * sizeof(float);
    float* statsAll = (float*)w; w += (size_t)L * 2 * H * sizeof(float);
    float* ss = (float*)w;       w += 2 * H * sizeof(float);
    int* deg = (int*)w;          w += (size_t)N * sizeof(int);
    int* offp = (int*)w;         w += (size_t)(N + 1) * sizeof(int);
    int* cursor = (int*)w;       w += (size_t)N * sizeof(int);
    int* bsum = (int*)w;         w += (size_t)numB * sizeof(int);
    int* srcl = (int*)w;         w += (size_t)E * sizeof(int);
    w = align_up(w, 256);
    char* Ws = w;                w += (size_t)L * 131072 + H * NODE_IN * 2;

    float* out = (float*)d_out;

    // ---- once-per-launch prep ----
    int wtotal = 2 * L * H * H2 + H * NODE_IN;
    convert_weights_kernel<<<(wtotal + 255) / 256, 256, 0, stream>>>(W1, W2, embW, Ws, L);
    embed_kernel<<<(N + 127) / 128, 512, 0, stream>>>(
        x, Ws + (size_t)L * 131072, embb, hbuf, N);

    hipMemsetAsync(deg, 0, (size_t)N * sizeof(int), stream);
    hipMemsetAsync(statsAll, 0, (size_t)L * 2 * H * sizeof(float), stream);

    hist_kernel<<<(E + 255) / 256, 256, 0, stream>>>(dst, deg, E);
    scan_partial_kernel<<<numB, 256, 0, stream>>>(deg, bsum, N);
    scan_bsum_kernel<<<1, 256, 0, stream>>>(bsum, offp + N, numB);
    scan_apply_kernel<<<numB, 256, 0, stream>>>(deg, bsum, offp, cursor, N);
    fill_kernel<<<(E + 255) / 256, 256, 0, stream>>>(src, dst, cursor, srcl, E);

    int agrid = (int)(((size_t)N * (H / 8) + 255) / 256);

    for (int l = 0; l < L; ++l) {
        float* stats = statsAll + (size_t)l * 2 * H;
        gin_layer_kernel<<<nblk, 512, 0, stream>>>(
            hbuf, zpb, offp, srcl,
            Ws + (size_t)l * 131072, b1 + (size_t)l * H2,
            b2 + (size_t)l * H, spart, N);
        reduce_stats_kernel<<<64, 256, 0, stream>>>(spart, stats, nblk);
        bn_finalize_kernel<<<1, H, 0, stream>>>(
            stats, gamma + (size_t)l * H, beta + (size_t)l * H, ss, N);
        if (l < L - 1)
            bn_apply_bf16_kernel<<<agrid, 256, 0, stream>>>(zpb, ss, hbuf, N);
        else
            bn_apply_kernel<<<agrid, 256, 0, stream>>>(zpb, ss, out, N);
    }
}

// Round 17
// 364.454 us; speedup vs baseline: 1.1950x; 1.1950x over previous
//
#include <hip/hip_runtime.h>

#define H 128
#define H2 256
#define NODE_IN 32
#define BN_EPS 1e-5f

typedef __bf16 bf16x8 __attribute__((ext_vector_type(8)));
typedef __bf16 bf16x4 __attribute__((ext_vector_type(4)));
typedef float f32x4 __attribute__((ext_vector_type(4)));

#define MFMA(a, b, c) __builtin_amdgcn_mfma_f32_16x16x32_bf16(a, b, c, 0, 0, 0)

// ---------------------------------------------------------------------------
// Weights -> bf16, transposed, XOR-swizzled GLOBAL layout.
// W1 [L][128][256] -> per layer at l*131072       : row n(0..255) x 256B
// W2 [L][256][128] -> per layer at l*131072+65536 : row n(0..127) x 512B
// embW [32][128]   -> at L*131072: Wt_e[c][k], row c(0..127) x 64B (no swizzle)
// Swizzle: 16B chunk c' = c ^ (n & 7) within each row.
__global__ __launch_bounds__(256) void convert_weights_kernel(
    const float* __restrict__ W1, const float* __restrict__ W2,
    const float* __restrict__ embW, char* __restrict__ Ws, int L)
{
    int idx = blockIdx.x * 256 + threadIdx.x;
    int per = H * H2;
    int total = L * per;
    if (idx < total) {
        int l = idx / per, r = idx % per;
        int k = r / H2, n = r % H2;          // W1[l][k][n]
        int c = k >> 3, e = k & 7;
        size_t off = (size_t)l * 131072 + n * 256 + (((c ^ (n & 7)) << 4)) + e * 2;
        *(__bf16*)(Ws + off) = (__bf16)W1[idx];
    } else if (idx < 2 * total) {
        int j = idx - total;
        int l = j / per, r = j % per;
        int k = r / H, n = r % H;            // W2[l][k][n]
        int c = k >> 3, e = k & 7;
        size_t off = (size_t)l * 131072 + 65536 + n * 512 + (((c ^ (n & 7)) << 4)) + e * 2;
        *(__bf16*)(Ws + off) = (__bf16)W2[j];
    } else if (idx < 2 * total + H * NODE_IN) {
        int j = idx - 2 * total;
        int k = j / H, c = j % H;            // embW[k][c]
        size_t off = (size_t)L * 131072 + c * 64 + k * 2;
        *(__bf16*)(Ws + off) = (__bf16)embW[j];
    }
}

// ---------------------------------------------------------------------------
// h0 = x @ emb_W + emb_b via MFMA (K=32 = one mfma_16x16x32).
__global__ __launch_bounds__(512) void embed_kernel(
    const float* __restrict__ x, const char* __restrict__ Wse,
    const float* __restrict__ bias, __bf16* __restrict__ h, int N)
{
    int tid = threadIdx.x;
    int w = tid >> 6, lane = tid & 63;
    int l15 = lane & 15, kg = lane >> 4;

    bf16x8 aw[8];
#pragma unroll
    for (int nt = 0; nt < 8; ++nt)
        aw[nt] = *(const bf16x8*)(Wse + (nt * 16 + l15) * 64 + kg * 16);

    int r = (blockIdx.x * 8 + w) * 16 + l15;
    bool ok = (r < N);

    bf16x8 xb = {};
    if (ok) {
        float4 v0 = *(const float4*)&x[(size_t)r * NODE_IN + kg * 8];
        float4 v1 = *(const float4*)&x[(size_t)r * NODE_IN + kg * 8 + 4];
        xb[0] = (__bf16)v0.x; xb[1] = (__bf16)v0.y;
        xb[2] = (__bf16)v0.z; xb[3] = (__bf16)v0.w;
        xb[4] = (__bf16)v1.x; xb[5] = (__bf16)v1.y;
        xb[6] = (__bf16)v1.z; xb[7] = (__bf16)v1.w;
    }

    __bf16* hr = h + (size_t)r * H;
#pragma unroll
    for (int nt = 0; nt < 8; ++nt) {
        f32x4 acc = {0.f, 0.f, 0.f, 0.f};
        acc = MFMA(aw[nt], xb, acc);
        if (ok) {
            float4 bb = *(const float4*)&bias[nt * 16 + kg * 4];
            bf16x4 hv;
            hv[0] = (__bf16)(acc[0] + bb.x);
            hv[1] = (__bf16)(acc[1] + bb.y);
            hv[2] = (__bf16)(acc[2] + bb.z);
            hv[3] = (__bf16)(acc[3] + bb.w);
            *(bf16x4*)(hr + nt * 16 + kg * 4) = hv;
        }
    }
}

// ---------------------------------------------------------------------------
// CSR build
__global__ __launch_bounds__(256) void hist_kernel(
    const int* __restrict__ dst, int* __restrict__ deg, int E)
{
    int e = blockIdx.x * 256 + threadIdx.x;
    if (e < E) atomicAdd(&deg[dst[e]], 1);
}

__global__ __launch_bounds__(256) void scan_partial_kernel(
    const int* __restrict__ deg, int* __restrict__ bsum, int N)
{
    __shared__ int red[256];
    int b = blockIdx.x, t = threadIdx.x;
    int base = b * 2048 + t * 8;
    int s = 0;
#pragma unroll
    for (int i = 0; i < 8; ++i) { int idx = base + i; if (idx < N) s += deg[idx]; }
    red[t] = s;
    __syncthreads();
    for (int d = 128; d > 0; d >>= 1) {
        if (t < d) red[t] += red[t + d];
        __syncthreads();
    }
    if (t == 0) bsum[b] = red[0];
}

__global__ __launch_bounds__(256) void scan_bsum_kernel(
    int* __restrict__ bsum, int* __restrict__ total, int numB)
{
    __shared__ int ts[256];
    int t = threadIdx.x;
    int v = (t < numB) ? bsum[t] : 0;
    ts[t] = v;
    __syncthreads();
    for (int d = 1; d < 256; d <<= 1) {
        int u = (t >= d) ? ts[t - d] : 0;
        __syncthreads();
        ts[t] += u;
        __syncthreads();
    }
    if (t < numB) bsum[t] = ts[t] - v;
    if (t == 255) *total = ts[255];
}

__global__ __launch_bounds__(256) void scan_apply_kernel(
    const int* __restrict__ deg, const int* __restrict__ bsum,
    int* __restrict__ offp, int* __restrict__ cursor, int N)
{
    __shared__ int ts[256];
    int b = blockIdx.x, t = threadIdx.x;
    int base = b * 2048 + t * 8;
    int loc[8];
    int s = 0;
#pragma unroll
    for (int i = 0; i < 8; ++i) {
        int idx = base + i;
        loc[i] = (idx < N) ? deg[idx] : 0;
        s += loc[i];
    }
    ts[t] = s;
    __syncthreads();
    for (int d = 1; d < 256; d <<= 1) {
        int u = (t >= d) ? ts[t - d] : 0;
        __syncthreads();
        ts[t] += u;
        __syncthreads();
    }
    int run = bsum[b] + ts[t] - s;
#pragma unroll
    for (int i = 0; i < 8; ++i) {
        int idx = base + i;
        if (idx < N) { offp[idx] = run; cursor[idx] = run; }
        run += loc[i];
    }
}

__global__ __launch_bounds__(256) void fill_kernel(
    const int* __restrict__ src, const int* __restrict__ dst,
    int* __restrict__ cursor, int* __restrict__ srclist, int E)
{
    int e = blockIdx.x * 256 + threadIdx.x;
    if (e < E) {
        int pos = atomicAdd(&cursor[dst[e]], 1);
        srclist[pos] = src[e];
    }
}

// ---------------------------------------------------------------------------
__device__ __forceinline__ uint32_t pack_relu2(float x, float y) {
    __bf16 a = (__bf16)fmaxf(x, 0.f), b = (__bf16)fmaxf(y, 0.f);
    return (uint32_t)__builtin_bit_cast(uint16_t, a) |
           ((uint32_t)__builtin_bit_cast(uint16_t, b) << 16);
}

// ---------------------------------------------------------------------------
// Fused GIN layer: gather (+inline-BN+ReLU of prev layer) -> LDS tile ->
// relu(z@W1+b1)@W2+b2 -> hout (pre-BN) + BN partial stats direct to spart.
// Block = 8 waves x 64 rows. BN coefs computed inline from stats/gamma/beta.
// Both gather row-groups' offp/self loads hoisted (latency overlap).
template <int BN>
__global__ __launch_bounds__(512, 4) void gin_layer_kernel(
    const __bf16* __restrict__ hin, __bf16* __restrict__ hout,
    const float* __restrict__ stats, const float* __restrict__ gammaP,
    const float* __restrict__ betaP, float invN,
    const int* __restrict__ offp, const int* __restrict__ srclist,
    const char* __restrict__ Ws, const float* __restrict__ b1l,
    const float* __restrict__ b2l, float* __restrict__ spart, int N)
{
    __shared__ __align__(16) char zt[16384];   // 64 rows x 256B, swizzled
    __shared__ __align__(16) char hl[32768];   // 64 rows x 512B, swizzled

    int tid = threadIdx.x;
    int w = tid >> 6, lane = tid & 63;
    int l15 = lane & 15, kg = lane >> 4;
    const int xsw = (l15 & 7) << 4;
    int r0g = blockIdx.x * 64;

    // ---- phase-1 weight frags issued early (hide L2 latency under gather) --
    bf16x8 aW1[2][4];
#pragma unroll
    for (int nt = 0; nt < 2; ++nt)
#pragma unroll
        for (int kk = 0; kk < 4; ++kk)
            aW1[nt][kk] = *(const bf16x8*)(
                Ws + (w * 32 + nt * 16 + l15) * 256 + ((((kk * 4 + kg) << 4)) ^ xsw));
    float4 bb1[2];
#pragma unroll
    for (int nt = 0; nt < 2; ++nt)
        bb1[nt] = *(const float4*)&b1l[w * 32 + nt * 16 + kg * 4];

    // ---- BN coefs inline (cols l15*8 .. l15*8+8) ----
    float sc[8], sh[8];
    if (BN) {
#pragma unroll
        for (int j = 0; j < 8; ++j) {
            int c = l15 * 8 + j;
            float mean = stats[c] * invN;
            float var = stats[H + c] * invN - mean * mean;
            float s = gammaP[c] * rsqrtf(var + BN_EPS);
            sc[j] = s;
            sh[j] = betaP[c] - mean * s;
        }
    }

    // ---- gather: wave w fills local rows [w*8, w*8+8) of zt ----
    // Rows rlA = w*8+kg and rlB = w*8+4+kg; both groups' offp/self hoisted.
    {
        int rlA = w * 8 + kg, rlB = rlA + 4;
        int rA = r0g + rlA, rB = r0g + rlB;
        bool okA = (rA < N), okB = (rB < N);
        int iA0 = 0, iA1 = 0, iB0 = 0, iB1 = 0;
        bf16x8 svA = {}, svB = {};
        if (okA) {
            iA0 = offp[rA]; iA1 = offp[rA + 1];
            svA = *(const bf16x8*)(hin + (size_t)rA * H + l15 * 8);
        }
        if (okB) {
            iB0 = offp[rB]; iB1 = offp[rB + 1];
            svB = *(const bf16x8*)(hin + (size_t)rB * H + l15 * 8);
        }

        // group A
        {
            bf16x8 o = {};
            if (okA) {
                float acc[8];
#pragma unroll
                for (int j = 0; j < 8; ++j) {
                    float f = (float)svA[j];
                    acc[j] = BN ? fmaxf(f * sc[j] + sh[j], 0.f) : f;
                }
                int i = iA0;
                for (; i + 3 < iA1; i += 4) {
                    int s0 = srclist[i], s1 = srclist[i + 1];
                    int s2 = srclist[i + 2], s3 = srclist[i + 3];
                    bf16x8 u0 = *(const bf16x8*)(hin + (size_t)s0 * H + l15 * 8);
                    bf16x8 u1 = *(const bf16x8*)(hin + (size_t)s1 * H + l15 * 8);
                    bf16x8 u2 = *(const bf16x8*)(hin + (size_t)s2 * H + l15 * 8);
                    bf16x8 u3 = *(const bf16x8*)(hin + (size_t)s3 * H + l15 * 8);
#pragma unroll
                    for (int j = 0; j < 8; ++j) {
                        float f0 = (float)u0[j], f1 = (float)u1[j];
                        float f2 = (float)u2[j], f3 = (float)u3[j];
                        if (BN) {
                            f0 = fmaxf(f0 * sc[j] + sh[j], 0.f);
                            f1 = fmaxf(f1 * sc[j] + sh[j], 0.f);
                            f2 = fmaxf(f2 * sc[j] + sh[j], 0.f);
                            f3 = fmaxf(f3 * sc[j] + sh[j], 0.f);
                        }
                        acc[j] += (f0 + f1) + (f2 + f3);
                    }
                }
                for (; i < iA1; ++i) {
                    int s0 = srclist[i];
                    bf16x8 u0 = *(const bf16x8*)(hin + (size_t)s0 * H + l15 * 8);
#pragma unroll
                    for (int j = 0; j < 8; ++j) {
                        float f0 = (float)u0[j];
                        if (BN) f0 = fmaxf(f0 * sc[j] + sh[j], 0.f);
                        acc[j] += f0;
                    }
                }
#pragma unroll
                for (int j = 0; j < 8; ++j) o[j] = (__bf16)acc[j];
            }
            int chunk = l15 ^ (rlA & 7);
            *(bf16x8*)(zt + rlA * 256 + chunk * 16) = o;
        }

        // group B
        {
            bf16x8 o = {};
            if (okB) {
                float acc[8];
#pragma unroll
                for (int j = 0; j < 8; ++j) {
                    float f = (float)svB[j];
                    acc[j] = BN ? fmaxf(f * sc[j] + sh[j], 0.f) : f;
                }
                int i = iB0;
                for (; i + 3 < iB1; i += 4) {
                    int s0 = srclist[i], s1 = srclist[i + 1];
                    int s2 = srclist[i + 2], s3 = srclist[i + 3];
                    bf16x8 u0 = *(const bf16x8*)(hin + (size_t)s0 * H + l15 * 8);
                    bf16x8 u1 = *(const bf16x8*)(hin + (size_t)s1 * H + l15 * 8);
                    bf16x8 u2 = *(const bf16x8*)(hin + (size_t)s2 * H + l15 * 8);
                    bf16x8 u3 = *(const bf16x8*)(hin + (size_t)s3 * H + l15 * 8);
#pragma unroll
                    for (int j = 0; j < 8; ++j) {
                        float f0 = (float)u0[j], f1 = (float)u1[j];
                        float f2 = (float)u2[j], f3 = (float)u3[j];
                        if (BN) {
                            f0 = fmaxf(f0 * sc[j] + sh[j], 0.f);
                            f1 = fmaxf(f1 * sc[j] + sh[j], 0.f);
                            f2 = fmaxf(f2 * sc[j] + sh[j], 0.f);
                            f3 = fmaxf(f3 * sc[j] + sh[j], 0.f);
                        }
                        acc[j] += (f0 + f1) + (f2 + f3);
                    }
                }
                for (; i < iB1; ++i) {
                    int s0 = srclist[i];
                    bf16x8 u0 = *(const bf16x8*)(hin + (size_t)s0 * H + l15 * 8);
#pragma unroll
                    for (int j = 0; j < 8; ++j) {
                        float f0 = (float)u0[j];
                        if (BN) f0 = fmaxf(f0 * sc[j] + sh[j], 0.f);
                        acc[j] += f0;
                    }
                }
#pragma unroll
                for (int j = 0; j < 8; ++j) o[j] = (__bf16)acc[j];
            }
            int chunk = l15 ^ (rlB & 7);
            *(bf16x8*)(zt + rlB * 256 + chunk * 16) = o;
        }
    }
    __syncthreads();   // zt complete

    // ---- phase 1: GEMM1 from LDS zt into LDS hid ----
#pragma unroll 1
    for (int i = 0; i < 4; ++i) {
        int rl = i * 16 + l15;
        bf16x8 zb[4];
#pragma unroll
        for (int kk = 0; kk < 4; ++kk)
            zb[kk] = *(const bf16x8*)(zt + rl * 256 + ((((kk * 4 + kg) << 4)) ^ xsw));
#pragma unroll
        for (int nt = 0; nt < 2; ++nt) {
            f32x4 a = {0.f, 0.f, 0.f, 0.f};
            a = MFMA(aW1[nt][0], zb[0], a);
            a = MFMA(aW1[nt][1], zb[1], a);
            a = MFMA(aW1[nt][2], zb[2], a);
            a = MFMA(aW1[nt][3], zb[3], a);
            uint32_t p0 = pack_relu2(a[0] + bb1[nt].x, a[1] + bb1[nt].y);
            uint32_t p1 = pack_relu2(a[2] + bb1[nt].z, a[3] + bb1[nt].w);
            int chunk = (w * 4 + nt * 2 + (kg >> 1)) ^ (l15 & 7);
            uint32_t* dstp = (uint32_t*)(hl + rl * 512 + chunk * 16 + (kg & 1) * 8);
            dstp[0] = p0;
            dstp[1] = p1;
        }
    }

    // ---- phase 2 weights/bias (aW1 dead; aW2 replaces it) ----
    bf16x8 aW2[8];
#pragma unroll
    for (int kk = 0; kk < 8; ++kk)
        aW2[kk] = *(const bf16x8*)(
            Ws + 65536 + (w * 16 + l15) * 512 + ((((kk * 4 + kg) << 4)) ^ xsw));
    float4 bb2 = *(const float4*)&b2l[w * 16 + kg * 4];

    __syncthreads();   // hid complete

    // ---- phase 2: GEMM2 from LDS hid; wave w owns out cols [w*16,w*16+16) --
    float ps0 = 0.f, ps1 = 0.f, ps2 = 0.f, ps3 = 0.f;
    float pq0 = 0.f, pq1 = 0.f, pq2 = 0.f, pq3 = 0.f;
#pragma unroll 1
    for (int i = 0; i < 4; ++i) {
        int r = r0g + i * 16 + l15;
        bool ok = (r < N);
        int rl = i * 16 + l15;
        bf16x8 bd[8];
#pragma unroll
        for (int kk = 0; kk < 8; ++kk)
            bd[kk] = *(const bf16x8*)(hl + rl * 512 + ((((kk * 4 + kg) << 4)) ^ xsw));
        f32x4 c = {0.f, 0.f, 0.f, 0.f};
#pragma unroll
        for (int kk = 0; kk < 8; ++kk) c = MFMA(aW2[kk], bd[kk], c);
        if (ok) {
            float v0 = c[0] + bb2.x, v1 = c[1] + bb2.y;
            float v2 = c[2] + bb2.z, v3 = c[3] + bb2.w;
            bf16x4 ov;
            ov[0] = (__bf16)v0; ov[1] = (__bf16)v1;
            ov[2] = (__bf16)v2; ov[3] = (__bf16)v3;
            *(bf16x4*)(hout + (size_t)r * H + w * 16 + kg * 4) = ov;
            ps0 += v0; pq0 += v0 * v0;
            ps1 += v1; pq1 += v1 * v1;
            ps2 += v2; pq2 += v2 * v2;
            ps3 += v3; pq3 += v3 * v3;
        }
    }

    // reduce over the 16 l15-lanes; wave-disjoint cols -> direct global write
    ps0 += __shfl_xor(ps0, 1, 64); ps0 += __shfl_xor(ps0, 2, 64);
    ps0 += __shfl_xor(ps0, 4, 64); ps0 += __shfl_xor(ps0, 8, 64);
    ps1 += __shfl_xor(ps1, 1, 64); ps1 += __shfl_xor(ps1, 2, 64);
    ps1 += __shfl_xor(ps1, 4, 64); ps1 += __shfl_xor(ps1, 8, 64);
    ps2 += __shfl_xor(ps2, 1, 64); ps2 += __shfl_xor(ps2, 2, 64);
    ps2 += __shfl_xor(ps2, 4, 64); ps2 += __shfl_xor(ps2, 8, 64);
    ps3 += __shfl_xor(ps3, 1, 64); ps3 += __shfl_xor(ps3, 2, 64);
    ps3 += __shfl_xor(ps3, 4, 64); ps3 += __shfl_xor(ps3, 8, 64);
    pq0 += __shfl_xor(pq0, 1, 64); pq0 += __shfl_xor(pq0, 2, 64);
    pq0 += __shfl_xor(pq0, 4, 64); pq0 += __shfl_xor(pq0, 8, 64);
    pq1 += __shfl_xor(pq1, 1, 64); pq1 += __shfl_xor(pq1, 2, 64);
    pq1 += __shfl_xor(pq1, 4, 64); pq1 += __shfl_xor(pq1, 8, 64);
    pq2 += __shfl_xor(pq2, 1, 64); pq2 += __shfl_xor(pq2, 2, 64);
    pq2 += __shfl_xor(pq2, 4, 64); pq2 += __shfl_xor(pq2, 8, 64);
    pq3 += __shfl_xor(pq3, 1, 64); pq3 += __shfl_xor(pq3, 2, 64);
    pq3 += __shfl_xor(pq3, 4, 64); pq3 += __shfl_xor(pq3, 8, 64);
    if (l15 == 0) {
        size_t row = (size_t)blockIdx.x * 256;
        int cb = w * 16 + kg * 4;
        *(float4*)&spart[row + cb] = make_float4(ps0, ps1, ps2, ps3);
        *(float4*)&spart[row + H + cb] = make_float4(pq0, pq1, pq2, pq3);
    }
}

// ---------------------------------------------------------------------------
__global__ __launch_bounds__(256) void reduce_stats_kernel(
    const float* __restrict__ spart, float* __restrict__ stats, int R)
{
    int t = threadIdx.x;
    int b = blockIdx.x;
    int per = (R + gridDim.x - 1) / gridDim.x;
    int r0 = b * per, r1 = r0 + per;
    if (r1 > R) r1 = R;
    float s = 0.f;
    for (int r = r0; r < r1; ++r) s += spart[(size_t)r * 256 + t];
    atomicAdd(&stats[t], s);
}

// ---------------------------------------------------------------------------
// out = relu(BN(zpb)) with BN coefs computed inline; bf16 -> fp32 (final)
__global__ __launch_bounds__(256) void bn_apply_kernel(
    const __bf16* __restrict__ zpb, const float* __restrict__ stats,
    const float* __restrict__ gammaP, const float* __restrict__ betaP,
    float invN, float* __restrict__ out, int N)
{
    size_t i = (size_t)blockIdx.x * 256 + threadIdx.x;   // 8-elem units
    size_t total = (size_t)N * (H / 8);
    if (i >= total) return;
    int c8 = (int)(i & (H / 8 - 1));
    bf16x8 v = *(const bf16x8*)(zpb + i * 8);
    float4 o0, o1;
    float o[8];
#pragma unroll
    for (int j = 0; j < 8; ++j) {
        int c = c8 * 8 + j;
        float mean = stats[c] * invN;
        float var = stats[H + c] * invN - mean * mean;
        float s = gammaP[c] * rsqrtf(var + BN_EPS);
        float sh = betaP[c] - mean * s;
        o[j] = fmaxf((float)v[j] * s + sh, 0.f);
    }
    o0.x = o[0]; o0.y = o[1]; o0.z = o[2]; o0.w = o[3];
    o1.x = o[4]; o1.y = o[5]; o1.z = o[6]; o1.w = o[7];
    ((float4*)out)[i * 2] = o0;
    ((float4*)out)[i * 2 + 1] = o1;
}

// ---------------------------------------------------------------------------
static inline char* align_up(char* p, size_t a) {
    return (char*)(((uintptr_t)p + a - 1) & ~(uintptr_t)(a - 1));
}

extern "C" void kernel_launch(void* const* d_in, const int* in_sizes, int n_in,
                              void* d_out, int out_size, void* d_ws, size_t ws_size,
                              hipStream_t stream)
{
    const float* x    = (const float*)d_in[0];
    const int*   ei   = (const int*)d_in[1];
    const float* embW = (const float*)d_in[2];
    const float* embb = (const float*)d_in[3];
    const float* W1   = (const float*)d_in[4];
    const float* b1   = (const float*)d_in[5];
    const float* W2   = (const float*)d_in[6];
    const float* b2   = (const float*)d_in[7];
    const float* gamma= (const float*)d_in[8];
    const float* beta = (const float*)d_in[9];

    int N = in_sizes[0] / NODE_IN;
    int E = in_sizes[1] / 2;
    int L = in_sizes[4] / (H * H2);
    const int* src = ei;
    const int* dst = ei + E;
    float invN = 1.0f / (float)N;

    int numB = (N + 2047) / 2048;
    int nblk = (N + 63) / 64;        // 64 rows per block

    char* w = (char*)d_ws;
    __bf16* bufA = (__bf16*)w;   w += (size_t)N * H * sizeof(__bf16);
    w = align_up(w, 256);
    __bf16* bufB = (__bf16*)w;   w += (size_t)N * H * sizeof(__bf16);
    w = align_up(w, 256);
    float* spart = (float*)w;    w += (size_t)nblk * 256 * sizeof(float);
    float* statsAll = (float*)w; w += (size_t)L * 2 * H * sizeof(float);
    int* deg = (int*)w;          w += (size_t)N * sizeof(int);
    int* offp = (int*)w;         w += (size_t)(N + 1) * sizeof(int);
    int* cursor = (int*)w;       w += (size_t)N * sizeof(int);
    int* bsum = (int*)w;         w += (size_t)numB * sizeof(int);
    int* srcl = (int*)w;         w += (size_t)E * sizeof(int);
    w = align_up(w, 256);
    char* Ws = w;                w += (size_t)L * 131072 + H * NODE_IN * 2;

    float* out = (float*)d_out;
    __bf16* buf[2] = {bufA, bufB};

    // ---- once-per-launch prep ----
    int wtotal = 2 * L * H * H2 + H * NODE_IN;
    convert_weights_kernel<<<(wtotal + 255) / 256, 256, 0, stream>>>(W1, W2, embW, Ws, L);
    embed_kernel<<<(N + 127) / 128, 512, 0, stream>>>(
        x, Ws + (size_t)L * 131072, embb, bufA, N);

    hipMemsetAsync(deg, 0, (size_t)N * sizeof(int), stream);
    hipMemsetAsync(statsAll, 0, (size_t)L * 2 * H * sizeof(float), stream);

    hist_kernel<<<(E + 255) / 256, 256, 0, stream>>>(dst, deg, E);
    scan_partial_kernel<<<numB, 256, 0, stream>>>(deg, bsum, N);
    scan_bsum_kernel<<<1, 256, 0, stream>>>(bsum, offp + N, numB);
    scan_apply_kernel<<<numB, 256, 0, stream>>>(deg, bsum, offp, cursor, N);
    fill_kernel<<<(E + 255) / 256, 256, 0, stream>>>(src, dst, cursor, srcl, E);

    int agrid = (int)(((size_t)N * (H / 8) + 255) / 256);

    for (int l = 0; l < L; ++l) {
        float* stats = statsAll + (size_t)l * 2 * H;
        const __bf16* hin = buf[l & 1];
        __bf16* hout = buf[(l + 1) & 1];
        if (l == 0)
            gin_layer_kernel<0><<<nblk, 512, 0, stream>>>(
                hin, hout, nullptr, nullptr, nullptr, 0.f, offp, srcl,
                Ws + (size_t)l * 131072, b1 + (size_t)l * H2,
                b2 + (size_t)l * H, spart, N);
        else
            gin_layer_kernel<1><<<nblk, 512, 0, stream>>>(
                hin, hout, statsAll + (size_t)(l - 1) * 2 * H,
                gamma + (size_t)(l - 1) * H, beta + (size_t)(l - 1) * H, invN,
                offp, srcl,
                Ws + (size_t)l * 131072, b1 + (size_t)l * H2,
                b2 + (size_t)l * H, spart, N);
        reduce_stats_kernel<<<64, 256, 0, stream>>>(spart, stats, nblk);
    }
    bn_apply_kernel<<<agrid, 256, 0, stream>>>(
        buf[L & 1], statsAll + (size_t)(L - 1) * 2 * H,
        gamma + (size_t)(L - 1) * H, beta + (size_t)(L - 1) * H, invN, out, N);
}

// Round 18
// 352.438 us; speedup vs baseline: 1.2358x; 1.0341x over previous
//
#include <hip/hip_runtime.h>

#define H 128
#define H2 256
#define NODE_IN 32
#define BN_EPS 1e-5f

typedef __bf16 bf16x8 __attribute__((ext_vector_type(8)));
typedef __bf16 bf16x4 __attribute__((ext_vector_type(4)));
typedef float f32x4 __attribute__((ext_vector_type(4)));

#define MFMA(a, b, c) __builtin_amdgcn_mfma_f32_16x16x32_bf16(a, b, c, 0, 0, 0)

// ---------------------------------------------------------------------------
// Weights -> bf16, transposed, XOR-swizzled GLOBAL layout.
// W1 [L][128][256] -> per layer at l*131072       : row n(0..255) x 256B
// W2 [L][256][128] -> per layer at l*131072+65536 : row n(0..127) x 512B
// embW [32][128]   -> at L*131072: Wt_e[c][k], row c(0..127) x 64B (no swizzle)
// Swizzle: 16B chunk c' = c ^ (n & 7) within each row.
__global__ __launch_bounds__(256) void convert_weights_kernel(
    const float* __restrict__ W1, const float* __restrict__ W2,
    const float* __restrict__ embW, char* __restrict__ Ws, int L)
{
    int idx = blockIdx.x * 256 + threadIdx.x;
    int per = H * H2;
    int total = L * per;
    if (idx < total) {
        int l = idx / per, r = idx % per;
        int k = r / H2, n = r % H2;          // W1[l][k][n]
        int c = k >> 3, e = k & 7;
        size_t off = (size_t)l * 131072 + n * 256 + (((c ^ (n & 7)) << 4)) + e * 2;
        *(__bf16*)(Ws + off) = (__bf16)W1[idx];
    } else if (idx < 2 * total) {
        int j = idx - total;
        int l = j / per, r = j % per;
        int k = r / H, n = r % H;            // W2[l][k][n]
        int c = k >> 3, e = k & 7;
        size_t off = (size_t)l * 131072 + 65536 + n * 512 + (((c ^ (n & 7)) << 4)) + e * 2;
        *(__bf16*)(Ws + off) = (__bf16)W2[j];
    } else if (idx < 2 * total + H * NODE_IN) {
        int j = idx - 2 * total;
        int k = j / H, c = j % H;            // embW[k][c]
        size_t off = (size_t)L * 131072 + c * 64 + k * 2;
        *(__bf16*)(Ws + off) = (__bf16)embW[j];
    }
}

// ---------------------------------------------------------------------------
// h0 = x @ emb_W + emb_b via MFMA (K=32 = one mfma_16x16x32).
__global__ __launch_bounds__(512) void embed_kernel(
    const float* __restrict__ x, const char* __restrict__ Wse,
    const float* __restrict__ bias, __bf16* __restrict__ h, int N)
{
    int tid = threadIdx.x;
    int w = tid >> 6, lane = tid & 63;
    int l15 = lane & 15, kg = lane >> 4;

    bf16x8 aw[8];
#pragma unroll
    for (int nt = 0; nt < 8; ++nt)
        aw[nt] = *(const bf16x8*)(Wse + (nt * 16 + l15) * 64 + kg * 16);

    int r = (blockIdx.x * 8 + w) * 16 + l15;
    bool ok = (r < N);

    bf16x8 xb = {};
    if (ok) {
        float4 v0 = *(const float4*)&x[(size_t)r * NODE_IN + kg * 8];
        float4 v1 = *(const float4*)&x[(size_t)r * NODE_IN + kg * 8 + 4];
        xb[0] = (__bf16)v0.x; xb[1] = (__bf16)v0.y;
        xb[2] = (__bf16)v0.z; xb[3] = (__bf16)v0.w;
        xb[4] = (__bf16)v1.x; xb[5] = (__bf16)v1.y;
        xb[6] = (__bf16)v1.z; xb[7] = (__bf16)v1.w;
    }

    __bf16* hr = h + (size_t)r * H;
#pragma unroll
    for (int nt = 0; nt < 8; ++nt) {
        f32x4 acc = {0.f, 0.f, 0.f, 0.f};
        acc = MFMA(aw[nt], xb, acc);
        if (ok) {
            float4 bb = *(const float4*)&bias[nt * 16 + kg * 4];
            bf16x4 hv;
            hv[0] = (__bf16)(acc[0] + bb.x);
            hv[1] = (__bf16)(acc[1] + bb.y);
            hv[2] = (__bf16)(acc[2] + bb.z);
            hv[3] = (__bf16)(acc[3] + bb.w);
            *(bf16x4*)(hr + nt * 16 + kg * 4) = hv;
        }
    }
}

// ---------------------------------------------------------------------------
// CSR build
__global__ __launch_bounds__(256) void hist_kernel(
    const int* __restrict__ dst, int* __restrict__ deg, int E)
{
    int e = blockIdx.x * 256 + threadIdx.x;
    if (e < E) atomicAdd(&deg[dst[e]], 1);
}

__global__ __launch_bounds__(256) void scan_partial_kernel(
    const int* __restrict__ deg, int* __restrict__ bsum, int N)
{
    __shared__ int red[256];
    int b = blockIdx.x, t = threadIdx.x;
    int base = b * 2048 + t * 8;
    int s = 0;
#pragma unroll
    for (int i = 0; i < 8; ++i) { int idx = base + i; if (idx < N) s += deg[idx]; }
    red[t] = s;
    __syncthreads();
    for (int d = 128; d > 0; d >>= 1) {
        if (t < d) red[t] += red[t + d];
        __syncthreads();
    }
    if (t == 0) bsum[b] = red[0];
}

__global__ __launch_bounds__(256) void scan_bsum_kernel(
    int* __restrict__ bsum, int* __restrict__ total, int numB)
{
    __shared__ int ts[256];
    int t = threadIdx.x;
    int v = (t < numB) ? bsum[t] : 0;
    ts[t] = v;
    __syncthreads();
    for (int d = 1; d < 256; d <<= 1) {
        int u = (t >= d) ? ts[t - d] : 0;
        __syncthreads();
        ts[t] += u;
        __syncthreads();
    }
    if (t < numB) bsum[t] = ts[t] - v;
    if (t == 255) *total = ts[255];
}

__global__ __launch_bounds__(256) void scan_apply_kernel(
    const int* __restrict__ deg, const int* __restrict__ bsum,
    int* __restrict__ offp, int* __restrict__ cursor, int N)
{
    __shared__ int ts[256];
    int b = blockIdx.x, t = threadIdx.x;
    int base = b * 2048 + t * 8;
    int loc[8];
    int s = 0;
#pragma unroll
    for (int i = 0; i < 8; ++i) {
        int idx = base + i;
        loc[i] = (idx < N) ? deg[idx] : 0;
        s += loc[i];
    }
    ts[t] = s;
    __syncthreads();
    for (int d = 1; d < 256; d <<= 1) {
        int u = (t >= d) ? ts[t - d] : 0;
        __syncthreads();
        ts[t] += u;
        __syncthreads();
    }
    int run = bsum[b] + ts[t] - s;
#pragma unroll
    for (int i = 0; i < 8; ++i) {
        int idx = base + i;
        if (idx < N) { offp[idx] = run; cursor[idx] = run; }
        run += loc[i];
    }
}

__global__ __launch_bounds__(256) void fill_kernel(
    const int* __restrict__ src, const int* __restrict__ dst,
    int* __restrict__ cursor, int* __restrict__ srclist, int E)
{
    int e = blockIdx.x * 256 + threadIdx.x;
    if (e < E) {
        int pos = atomicAdd(&cursor[dst[e]], 1);
        srclist[pos] = src[e];
    }
}

// ---------------------------------------------------------------------------
__device__ __forceinline__ uint32_t pack_relu2(float x, float y) {
    __bf16 a = (__bf16)fmaxf(x, 0.f), b = (__bf16)fmaxf(y, 0.f);
    return (uint32_t)__builtin_bit_cast(uint16_t, a) |
           ((uint32_t)__builtin_bit_cast(uint16_t, b) << 16);
}

// ---------------------------------------------------------------------------
// Fused GIN layer: gather (+inline-BN+ReLU of prev layer) -> LDS tile ->
// relu(z@W1+b1)@W2+b2 -> hout (pre-BN) + BN partial stats direct to spart.
// Block = 8 waves x 64 rows. Gather's A/B row-group chains FULLY interleaved
// (fused main loop issues both srclist + both h-load sets -> ~half latency).
template <int BN>
__global__ __launch_bounds__(512, 4) void gin_layer_kernel(
    const __bf16* __restrict__ hin, __bf16* __restrict__ hout,
    const float* __restrict__ stats, const float* __restrict__ gammaP,
    const float* __restrict__ betaP, float invN,
    const int* __restrict__ offp, const int* __restrict__ srclist,
    const char* __restrict__ Ws, const float* __restrict__ b1l,
    const float* __restrict__ b2l, float* __restrict__ spart, int N)
{
    __shared__ __align__(16) char zt[16384];   // 64 rows x 256B, swizzled
    __shared__ __align__(16) char hl[32768];   // 64 rows x 512B, swizzled

    int tid = threadIdx.x;
    int w = tid >> 6, lane = tid & 63;
    int l15 = lane & 15, kg = lane >> 4;
    const int xsw = (l15 & 7) << 4;
    int r0g = blockIdx.x * 64;

    // ---- gather: wave w fills local rows [w*8, w*8+8) of zt ----
    {
        // BN coefs inline (cols l15*8 .. l15*8+8); die before GEMM1
        float sc[8], sh[8];
        if (BN) {
#pragma unroll
            for (int j = 0; j < 8; ++j) {
                int c = l15 * 8 + j;
                float mean = stats[c] * invN;
                float var = stats[H + c] * invN - mean * mean;
                float s = gammaP[c] * rsqrtf(var + BN_EPS);
                sc[j] = s;
                sh[j] = betaP[c] - mean * s;
            }
        }

        int rlA = w * 8 + kg, rlB = rlA + 4;
        int rA = r0g + rlA, rB = r0g + rlB;
        bool okA = (rA < N), okB = (rB < N);
        int iA = 0, iA1 = 0, iB = 0, iB1 = 0;
        bf16x8 svA = {}, svB = {};
        if (okA) {
            iA = offp[rA]; iA1 = offp[rA + 1];
            svA = *(const bf16x8*)(hin + (size_t)rA * H + l15 * 8);
        }
        if (okB) {
            iB = offp[rB]; iB1 = offp[rB + 1];
            svB = *(const bf16x8*)(hin + (size_t)rB * H + l15 * 8);
        }

        float accA[8], accB[8];
#pragma unroll
        for (int j = 0; j < 8; ++j) {
            float fA = (float)svA[j], fB = (float)svB[j];
            accA[j] = BN ? fmaxf(fA * sc[j] + sh[j], 0.f) : fA;
            accB[j] = BN ? fmaxf(fB * sc[j] + sh[j], 0.f) : fB;
        }

        // fused main loop: both groups' chains in flight together
        while (iA + 3 < iA1 && iB + 3 < iB1) {
            int a0 = srclist[iA], a1 = srclist[iA + 1];
            int a2 = srclist[iA + 2], a3 = srclist[iA + 3];
            int b0 = srclist[iB], b1 = srclist[iB + 1];
            int b2 = srclist[iB + 2], b3 = srclist[iB + 3];
            bf16x8 uA0 = *(const bf16x8*)(hin + (size_t)a0 * H + l15 * 8);
            bf16x8 uA1 = *(const bf16x8*)(hin + (size_t)a1 * H + l15 * 8);
            bf16x8 uA2 = *(const bf16x8*)(hin + (size_t)a2 * H + l15 * 8);
            bf16x8 uA3 = *(const bf16x8*)(hin + (size_t)a3 * H + l15 * 8);
            bf16x8 uB0 = *(const bf16x8*)(hin + (size_t)b0 * H + l15 * 8);
            bf16x8 uB1 = *(const bf16x8*)(hin + (size_t)b1 * H + l15 * 8);
            bf16x8 uB2 = *(const bf16x8*)(hin + (size_t)b2 * H + l15 * 8);
            bf16x8 uB3 = *(const bf16x8*)(hin + (size_t)b3 * H + l15 * 8);
#pragma unroll
            for (int j = 0; j < 8; ++j) {
                float fa0 = (float)uA0[j], fa1 = (float)uA1[j];
                float fa2 = (float)uA2[j], fa3 = (float)uA3[j];
                float fb0 = (float)uB0[j], fb1 = (float)uB1[j];
                float fb2 = (float)uB2[j], fb3 = (float)uB3[j];
                if (BN) {
                    fa0 = fmaxf(fa0 * sc[j] + sh[j], 0.f);
                    fa1 = fmaxf(fa1 * sc[j] + sh[j], 0.f);
                    fa2 = fmaxf(fa2 * sc[j] + sh[j], 0.f);
                    fa3 = fmaxf(fa3 * sc[j] + sh[j], 0.f);
                    fb0 = fmaxf(fb0 * sc[j] + sh[j], 0.f);
                    fb1 = fmaxf(fb1 * sc[j] + sh[j], 0.f);
                    fb2 = fmaxf(fb2 * sc[j] + sh[j], 0.f);
                    fb3 = fmaxf(fb3 * sc[j] + sh[j], 0.f);
                }
                accA[j] += (fa0 + fa1) + (fa2 + fa3);
                accB[j] += (fb0 + fb1) + (fb2 + fb3);
            }
            iA += 4; iB += 4;
        }
        // drain A
        for (; iA + 3 < iA1; iA += 4) {
            int a0 = srclist[iA], a1 = srclist[iA + 1];
            int a2 = srclist[iA + 2], a3 = srclist[iA + 3];
            bf16x8 u0 = *(const bf16x8*)(hin + (size_t)a0 * H + l15 * 8);
            bf16x8 u1 = *(const bf16x8*)(hin + (size_t)a1 * H + l15 * 8);
            bf16x8 u2 = *(const bf16x8*)(hin + (size_t)a2 * H + l15 * 8);
            bf16x8 u3 = *(const bf16x8*)(hin + (size_t)a3 * H + l15 * 8);
#pragma unroll
            for (int j = 0; j < 8; ++j) {
                float f0 = (float)u0[j], f1 = (float)u1[j];
                float f2 = (float)u2[j], f3 = (float)u3[j];
                if (BN) {
                    f0 = fmaxf(f0 * sc[j] + sh[j], 0.f);
                    f1 = fmaxf(f1 * sc[j] + sh[j], 0.f);
                    f2 = fmaxf(f2 * sc[j] + sh[j], 0.f);
                    f3 = fmaxf(f3 * sc[j] + sh[j], 0.f);
                }
                accA[j] += (f0 + f1) + (f2 + f3);
            }
        }
        for (; iA < iA1; ++iA) {
            int a0 = srclist[iA];
            bf16x8 u0 = *(const bf16x8*)(hin + (size_t)a0 * H + l15 * 8);
#pragma unroll
            for (int j = 0; j < 8; ++j) {
                float f0 = (float)u0[j];
                if (BN) f0 = fmaxf(f0 * sc[j] + sh[j], 0.f);
                accA[j] += f0;
            }
        }
        // drain B
        for (; iB + 3 < iB1; iB += 4) {
            int b0 = srclist[iB], b1 = srclist[iB + 1];
            int b2 = srclist[iB + 2], b3 = srclist[iB + 3];
            bf16x8 u0 = *(const bf16x8*)(hin + (size_t)b0 * H + l15 * 8);
            bf16x8 u1 = *(const bf16x8*)(hin + (size_t)b1 * H + l15 * 8);
            bf16x8 u2 = *(const bf16x8*)(hin + (size_t)b2 * H + l15 * 8);
            bf16x8 u3 = *(const bf16x8*)(hin + (size_t)b3 * H + l15 * 8);
#pragma unroll
            for (int j = 0; j < 8; ++j) {
                float f0 = (float)u0[j], f1 = (float)u1[j];
                float f2 = (float)u2[j], f3 = (float)u3[j];
                if (BN) {
                    f0 = fmaxf(f0 * sc[j] + sh[j], 0.f);
                    f1 = fmaxf(f1 * sc[j] + sh[j], 0.f);
                    f2 = fmaxf(f2 * sc[j] + sh[j], 0.f);
                    f3 = fmaxf(f3 * sc[j] + sh[j], 0.f);
                }
                accB[j] += (f0 + f1) + (f2 + f3);
            }
        }
        for (; iB < iB1; ++iB) {
            int b0 = srclist[iB];
            bf16x8 u0 = *(const bf16x8*)(hin + (size_t)b0 * H + l15 * 8);
#pragma unroll
            for (int j = 0; j < 8; ++j) {
                float f0 = (float)u0[j];
                if (BN) f0 = fmaxf(f0 * sc[j] + sh[j], 0.f);
                accB[j] += f0;
            }
        }

        bf16x8 oA, oB;
#pragma unroll
        for (int j = 0; j < 8; ++j) {
            oA[j] = (__bf16)accA[j];
            oB[j] = (__bf16)accB[j];
        }
        if (!okA) oA = bf16x8{};
        if (!okB) oB = bf16x8{};
        *(bf16x8*)(zt + rlA * 256 + (l15 ^ (rlA & 7)) * 16) = oA;
        *(bf16x8*)(zt + rlB * 256 + (l15 ^ (rlB & 7)) * 16) = oB;
    }

    // ---- phase-1 weight frags (loads complete during barrier drain) ----
    bf16x8 aW1[2][4];
#pragma unroll
    for (int nt = 0; nt < 2; ++nt)
#pragma unroll
        for (int kk = 0; kk < 4; ++kk)
            aW1[nt][kk] = *(const bf16x8*)(
                Ws + (w * 32 + nt * 16 + l15) * 256 + ((((kk * 4 + kg) << 4)) ^ xsw));
    float4 bb1[2];
#pragma unroll
    for (int nt = 0; nt < 2; ++nt)
        bb1[nt] = *(const float4*)&b1l[w * 32 + nt * 16 + kg * 4];

    __syncthreads();   // zt complete

    // ---- phase 1: GEMM1 from LDS zt into LDS hid ----
#pragma unroll 1
    for (int i = 0; i < 4; ++i) {
        int rl = i * 16 + l15;
        bf16x8 zb[4];
#pragma unroll
        for (int kk = 0; kk < 4; ++kk)
            zb[kk] = *(const bf16x8*)(zt + rl * 256 + ((((kk * 4 + kg) << 4)) ^ xsw));
        __builtin_amdgcn_s_setprio(1);
#pragma unroll
        for (int nt = 0; nt < 2; ++nt) {
            f32x4 a = {0.f, 0.f, 0.f, 0.f};
            a = MFMA(aW1[nt][0], zb[0], a);
            a = MFMA(aW1[nt][1], zb[1], a);
            a = MFMA(aW1[nt][2], zb[2], a);
            a = MFMA(aW1[nt][3], zb[3], a);
            uint32_t p0 = pack_relu2(a[0] + bb1[nt].x, a[1] + bb1[nt].y);
            uint32_t p1 = pack_relu2(a[2] + bb1[nt].z, a[3] + bb1[nt].w);
            int chunk = (w * 4 + nt * 2 + (kg >> 1)) ^ (l15 & 7);
            uint32_t* dstp = (uint32_t*)(hl + rl * 512 + chunk * 16 + (kg & 1) * 8);
            dstp[0] = p0;
            dstp[1] = p1;
        }
        __builtin_amdgcn_s_setprio(0);
    }

    // ---- phase 2 weights/bias (aW1 dead; aW2 replaces it) ----
    bf16x8 aW2[8];
#pragma unroll
    for (int kk = 0; kk < 8; ++kk)
        aW2[kk] = *(const bf16x8*)(
            Ws + 65536 + (w * 16 + l15) * 512 + ((((kk * 4 + kg) << 4)) ^ xsw));
    float4 bb2 = *(const float4*)&b2l[w * 16 + kg * 4];

    __syncthreads();   // hid complete

    // ---- phase 2: GEMM2 from LDS hid; wave w owns out cols [w*16,w*16+16) --
    float ps0 = 0.f, ps1 = 0.f, ps2 = 0.f, ps3 = 0.f;
    float pq0 = 0.f, pq1 = 0.f, pq2 = 0.f, pq3 = 0.f;
#pragma unroll 1
    for (int i = 0; i < 4; ++i) {
        int r = r0g + i * 16 + l15;
        bool ok = (r < N);
        int rl = i * 16 + l15;
        bf16x8 bd[8];
#pragma unroll
        for (int kk = 0; kk < 8; ++kk)
            bd[kk] = *(const bf16x8*)(hl + rl * 512 + ((((kk * 4 + kg) << 4)) ^ xsw));
        __builtin_amdgcn_s_setprio(1);
        f32x4 c = {0.f, 0.f, 0.f, 0.f};
#pragma unroll
        for (int kk = 0; kk < 8; ++kk) c = MFMA(aW2[kk], bd[kk], c);
        __builtin_amdgcn_s_setprio(0);
        if (ok) {
            float v0 = c[0] + bb2.x, v1 = c[1] + bb2.y;
            float v2 = c[2] + bb2.z, v3 = c[3] + bb2.w;
            bf16x4 ov;
            ov[0] = (__bf16)v0; ov[1] = (__bf16)v1;
            ov[2] = (__bf16)v2; ov[3] = (__bf16)v3;
            *(bf16x4*)(hout + (size_t)r * H + w * 16 + kg * 4) = ov;
            ps0 += v0; pq0 += v0 * v0;
            ps1 += v1; pq1 += v1 * v1;
            ps2 += v2; pq2 += v2 * v2;
            ps3 += v3; pq3 += v3 * v3;
        }
    }

    // reduce over the 16 l15-lanes; wave-disjoint cols -> direct global write
    ps0 += __shfl_xor(ps0, 1, 64); ps0 += __shfl_xor(ps0, 2, 64);
    ps0 += __shfl_xor(ps0, 4, 64); ps0 += __shfl_xor(ps0, 8, 64);
    ps1 += __shfl_xor(ps1, 1, 64); ps1 += __shfl_xor(ps1, 2, 64);
    ps1 += __shfl_xor(ps1, 4, 64); ps1 += __shfl_xor(ps1, 8, 64);
    ps2 += __shfl_xor(ps2, 1, 64); ps2 += __shfl_xor(ps2, 2, 64);
    ps2 += __shfl_xor(ps2, 4, 64); ps2 += __shfl_xor(ps2, 8, 64);
    ps3 += __shfl_xor(ps3, 1, 64); ps3 += __shfl_xor(ps3, 2, 64);
    ps3 += __shfl_xor(ps3, 4, 64); ps3 += __shfl_xor(ps3, 8, 64);
    pq0 += __shfl_xor(pq0, 1, 64); pq0 += __shfl_xor(pq0, 2, 64);
    pq0 += __shfl_xor(pq0, 4, 64); pq0 += __shfl_xor(pq0, 8, 64);
    pq1 += __shfl_xor(pq1, 1, 64); pq1 += __shfl_xor(pq1, 2, 64);
    pq1 += __shfl_xor(pq1, 4, 64); pq1 += __shfl_xor(pq1, 8, 64);
    pq2 += __shfl_xor(pq2, 1, 64); pq2 += __shfl_xor(pq2, 2, 64);
    pq2 += __shfl_xor(pq2, 4, 64); pq2 += __shfl_xor(pq2, 8, 64);
    pq3 += __shfl_xor(pq3, 1, 64); pq3 += __shfl_xor(pq3, 2, 64);
    pq3 += __shfl_xor(pq3, 4, 64); pq3 += __shfl_xor(pq3, 8, 64);
    if (l15 == 0) {
        size_t row = (size_t)blockIdx.x * 256;
        int cb = w * 16 + kg * 4;
        *(float4*)&spart[row + cb] = make_float4(ps0, ps1, ps2, ps3);
        *(float4*)&spart[row + H + cb] = make_float4(pq0, pq1, pq2, pq3);
    }
}

// ---------------------------------------------------------------------------
__global__ __launch_bounds__(256) void reduce_stats_kernel(
    const float* __restrict__ spart, float* __restrict__ stats, int R)
{
    int t = threadIdx.x;
    int b = blockIdx.x;
    int per = (R + gridDim.x - 1) / gridDim.x;
    int r0 = b * per, r1 = r0 + per;
    if (r1 > R) r1 = R;
    float s = 0.f;
    for (int r = r0; r < r1; ++r) s += spart[(size_t)r * 256 + t];
    atomicAdd(&stats[t], s);
}

// ---------------------------------------------------------------------------
// out = relu(BN(zpb)) with BN coefs computed inline; bf16 -> fp32 (final)
__global__ __launch_bounds__(256) void bn_apply_kernel(
    const __bf16* __restrict__ zpb, const float* __restrict__ stats,
    const float* __restrict__ gammaP, const float* __restrict__ betaP,
    float invN, float* __restrict__ out, int N)
{
    size_t i = (size_t)blockIdx.x * 256 + threadIdx.x;   // 8-elem units
    size_t total = (size_t)N * (H / 8);
    if (i >= total) return;
    int c8 = (int)(i & (H / 8 - 1));
    bf16x8 v = *(const bf16x8*)(zpb + i * 8);
    float4 o0, o1;
    float o[8];
#pragma unroll
    for (int j = 0; j < 8; ++j) {
        int c = c8 * 8 + j;
        float mean = stats[c] * invN;
        float var = stats[H + c] * invN - mean * mean;
        float s = gammaP[c] * rsqrtf(var + BN_EPS);
        float sh = betaP[c] - mean * s;
        o[j] = fmaxf((float)v[j] * s + sh, 0.f);
    }
    o0.x = o[0]; o0.y = o[1]; o0.z = o[2]; o0.w = o[3];
    o1.x = o[4]; o1.y = o[5]; o1.z = o[6]; o1.w = o[7];
    ((float4*)out)[i * 2] = o0;
    ((float4*)out)[i * 2 + 1] = o1;
}

// ---------------------------------------------------------------------------
static inline char* align_up(char* p, size_t a) {
    return (char*)(((uintptr_t)p + a - 1) & ~(uintptr_t)(a - 1));
}

extern "C" void kernel_launch(void* const* d_in, const int* in_sizes, int n_in,
                              void* d_out, int out_size, void* d_ws, size_t ws_size,
                              hipStream_t stream)
{
    const float* x    = (const float*)d_in[0];
    const int*   ei   = (const int*)d_in[1];
    const float* embW = (const float*)d_in[2];
    const float* embb = (const float*)d_in[3];
    const float* W1   = (const float*)d_in[4];
    const float* b1   = (const float*)d_in[5];
    const float* W2   = (const float*)d_in[6];
    const float* b2   = (const float*)d_in[7];
    const float* gamma= (const float*)d_in[8];
    const float* beta = (const float*)d_in[9];

    int N = in_sizes[0] / NODE_IN;
    int E = in_sizes[1] / 2;
    int L = in_sizes[4] / (H * H2);
    const int* src = ei;
    const int* dst = ei + E;
    float invN = 1.0f / (float)N;

    int numB = (N + 2047) / 2048;
    int nblk = (N + 63) / 64;        // 64 rows per block

    char* w = (char*)d_ws;
    __bf16* bufA = (__bf16*)w;   w += (size_t)N * H * sizeof(__bf16);
    w = align_up(w, 256);
    __bf16* bufB = (__bf16*)w;   w += (size_t)N * H * sizeof(__bf16);
    w = align_up(w, 256);
    float* spart = (float*)w;    w += (size_t)nblk * 256 * sizeof(float);
    float* statsAll = (float*)w; w += (size_t)L * 2 * H * sizeof(float);
    int* deg = (int*)w;          w += (size_t)N * sizeof(int);
    int* offp = (int*)w;         w += (size_t)(N + 1) * sizeof(int);
    int* cursor = (int*)w;       w += (size_t)N * sizeof(int);
    int* bsum = (int*)w;         w += (size_t)numB * sizeof(int);
    int* srcl = (int*)w;         w += (size_t)E * sizeof(int);
    w = align_up(w, 256);
    char* Ws = w;                w += (size_t)L * 131072 + H * NODE_IN * 2;

    float* out = (float*)d_out;
    __bf16* buf[2] = {bufA, bufB};

    // ---- once-per-launch prep ----
    int wtotal = 2 * L * H * H2 + H * NODE_IN;
    convert_weights_kernel<<<(wtotal + 255) / 256, 256, 0, stream>>>(W1, W2, embW, Ws, L);
    embed_kernel<<<(N + 127) / 128, 512, 0, stream>>>(
        x, Ws + (size_t)L * 131072, embb, bufA, N);

    hipMemsetAsync(deg, 0, (size_t)N * sizeof(int), stream);
    hipMemsetAsync(statsAll, 0, (size_t)L * 2 * H * sizeof(float), stream);

    hist_kernel<<<(E + 255) / 256, 256, 0, stream>>>(dst, deg, E);
    scan_partial_kernel<<<numB, 256, 0, stream>>>(deg, bsum, N);
    scan_bsum_kernel<<<1, 256, 0, stream>>>(bsum, offp + N, numB);
    scan_apply_kernel<<<numB, 256, 0, stream>>>(deg, bsum, offp, cursor, N);
    fill_kernel<<<(E + 255) / 256, 256, 0, stream>>>(src, dst, cursor, srcl, E);

    int agrid = (int)(((size_t)N * (H / 8) + 255) / 256);

    for (int l = 0; l < L; ++l) {
        float* stats = statsAll + (size_t)l * 2 * H;
        const __bf16* hin = buf[l & 1];
        __bf16* hout = buf[(l + 1) & 1];
        if (l == 0)
            gin_layer_kernel<0><<<nblk, 512, 0, stream>>>(
                hin, hout, nullptr, nullptr, nullptr, 0.f, offp, srcl,
                Ws + (size_t)l * 131072, b1 + (size_t)l * H2,
                b2 + (size_t)l * H, spart, N);
        else
            gin_layer_kernel<1><<<nblk, 512, 0, stream>>>(
                hin, hout, statsAll + (size_t)(l - 1) * 2 * H,
                gamma + (size_t)(l - 1) * H, beta + (size_t)(l - 1) * H, invN,
                offp, srcl,
                Ws + (size_t)l * 131072, b1 + (size_t)l * H2,
                b2 + (size_t)l * H, spart, N);
        reduce_stats_kernel<<<64, 256, 0, stream>>>(spart, stats, nblk);
    }
    bn_apply_kernel<<<agrid, 256, 0, stream>>>(
        buf[L & 1], statsAll + (size_t)(L - 1) * 2 * H,
        gamma + (size_t)(L - 1) * H, beta + (size_t)(L - 1) * H, invN, out, N);
}